// Round 13
// baseline (126.643 us; speedup 1.0000x reference)
//
#include <hip/hip_runtime.h>

typedef __attribute__((ext_vector_type(2))) float  f32x2;
typedef __attribute__((ext_vector_type(4))) float  f32x4;
typedef __attribute__((ext_vector_type(4))) unsigned int u32x4;
typedef _Float16 f16;
typedef __attribute__((ext_vector_type(2))) _Float16 f16x2;
typedef __attribute__((ext_vector_type(4))) _Float16 f16x4;
typedef __attribute__((ext_vector_type(8))) _Float16 f16x8;

#define S_LEN 2048
#define E_DIM 512
#define NH 64
#define DK 8

// ---------------------------------------------------------------------------
// Kernel 1: MFMA attention (R11 design, validated R12: ~25us vs 40us scalar).
// One wave = one token. S2 = Ps·Psᵀ (16 MFMA, K=8 in K=32), E = exp2(S2)
// written row-major via symmetry, D2 = [Pᵀ; ones]·Eᵀ (8 MFMA, row 8 = softmax
// denominators), bpermute + rcp + scaled f16x4 stores (nontemporal: consumer
// gemm reads A nontemporally, so don't allocate L2 lines for it).
// R13: blocks 0..255 additionally convert W fp32->f16 (1 float4/thread) —
// absorbs the convert_w dispatch + launch gap.
// A[row,col]: row = b*2048 + h*32 + s/64 ; col = (s%64)*8 + d  (f16)
// ---------------------------------------------------------------------------
__global__ __launch_bounds__(256) void attn_stage(
    const float* __restrict__ X,    // (8,2048,512) fp32
    const float* __restrict__ TH,   // (8,) fp32
    const float* __restrict__ W,    // (512,512) fp32
    f16* __restrict__ Wb,           // ws: 512x512 f16
    f16* __restrict__ A)            // ws: 16384 x 512 fp16
{
    __shared__ __align__(16) f16 Ps[4][NH][DK];   // 4 KB
    __shared__ __align__(16) f16 Pt[4][16][72];   // 9 KB
    __shared__ __align__(16) f16 Ev[4][NH * NH];  // 32 KB
    const int tid  = threadIdx.x;
    const int wv   = tid >> 6;
    const int lane = tid & 63;
    const int q    = lane >> 4;
    const int l    = lane & 15;
    const int t    = blockIdx.x * 4 + wv;    // token id

    // Side job: W fp32 -> f16 (65536 float4s == 256 blocks x 256 threads)
    if (blockIdx.x < 256) {
        const int i = blockIdx.x * 256 + tid;
        const float4 v = *(const float4*)(W + (size_t)i * 4);
        f16x4 o = {(f16)v.x, (f16)v.y, (f16)v.z, (f16)v.w};
        *(f16x4*)(Wb + (size_t)i * 4) = o;
    }

    const float4 t0 = *(const float4*)(TH);
    const float4 t1 = *(const float4*)(TH + 4);
    const float4 x0 = *(const float4*)(X + (size_t)t * E_DIM + lane * DK);
    const float4 x1 = *(const float4*)(X + (size_t)t * E_DIM + lane * DK + 4);

    float p[DK];
    p[0] = __cosf(x0.x + t0.x); p[1] = __cosf(x0.y + t0.y);
    p[2] = __cosf(x0.z + t0.z); p[3] = __cosf(x0.w + t0.w);
    p[4] = __cosf(x1.x + t1.x); p[5] = __cosf(x1.y + t1.y);
    p[6] = __cosf(x1.z + t1.z); p[7] = __cosf(x1.w + t1.w);

    // Ps[h][d] = p*cs  (cs^2 = (1/sqrt(8))*log2(e))
    const float cs = 0.714227053f;
    f16x8 psv;
    #pragma unroll
    for (int d = 0; d < DK; ++d) psv[d] = (f16)(p[d] * cs);
    *(f16x8*)&Ps[wv][lane][0] = psv;
    #pragma unroll
    for (int d = 0; d < DK; ++d) Pt[wv][d][lane] = (f16)p[d];
    __syncthreads();

    const f16x8 z8  = {(f16)0,(f16)0,(f16)0,(f16)0,(f16)0,(f16)0,(f16)0,(f16)0};
    const f16x8 one8= {(f16)1,(f16)1,(f16)1,(f16)1,(f16)1,(f16)1,(f16)1,(f16)1};

    f16x8 f[4];
    #pragma unroll
    for (int i = 0; i < 4; ++i) {
        const f16x8 v = *(const f16x8*)&Ps[wv][i*16 + l][0];
        f[i] = (q == 0) ? v : z8;
    }
    f32x4 St[4][4];
    #pragma unroll
    for (int i = 0; i < 4; ++i)
        #pragma unroll
        for (int jb = 0; jb < 4; ++jb) {
            f32x4 zc = {0.f, 0.f, 0.f, 0.f};
            St[i][jb] = __builtin_amdgcn_mfma_f32_16x16x32_f16(f[i], f[jb], zc, 0, 0, 0);
        }

    // E = exp2(S2), row-major via symmetry; chunk-8 XOR swizzle on cols.
    #pragma unroll
    for (int i = 0; i < 4; ++i)
        #pragma unroll
        for (int jb = 0; jb < 4; ++jb) {
            const float e0 = __builtin_amdgcn_exp2f(St[i][jb][0]);
            const float e1 = __builtin_amdgcn_exp2f(St[i][jb][1]);
            const float e2 = __builtin_amdgcn_exp2f(St[i][jb][2]);
            const float e3 = __builtin_amdgcn_exp2f(St[i][jb][3]);
            f16x4 w4;
            w4[0] = (f16)e0; w4[1] = (f16)e1; w4[2] = (f16)e2; w4[3] = (f16)e3;
            const int row = jb * 16 + l;
            const int c8  = (i * 2 + (q >> 1)) ^ (l & 7);
            const int col = c8 * 8 + (q & 1) * 4;
            *(f16x4*)&Ev[wv][row * 64 + col] = w4;
        }
    __syncthreads();

    // D2 = [Pᵀ; ones; 0]·Eᵀ over K=64.
    f32x4 d2[4] = {};
    #pragma unroll
    for (int kh = 0; kh < 2; ++kh) {
        const f16x8 av  = *(const f16x8*)&Pt[wv][l][kh * 32 + q * 8];
        const f16x8 a2f = (l < 8) ? av : ((l == 8) ? one8 : z8);
        #pragma unroll
        for (int nb = 0; nb < 4; ++nb) {
            const int c8 = (kh * 4 + q) ^ (l & 7);
            const f16x8 bv = *(const f16x8*)&Ev[wv][(nb * 16 + l) * 64 + c8 * 8];
            d2[nb] = __builtin_amdgcn_mfma_f32_16x16x32_f16(a2f, bv, d2[nb], 0, 0, 0);
        }
    }

    float rsinv[4];
    #pragma unroll
    for (int nb = 0; nb < 4; ++nb) {
        const int rs = __builtin_amdgcn_ds_bpermute((32 + l) * 4,
                           __float_as_int(d2[nb][0]));
        rsinv[nb] = __builtin_amdgcn_rcpf(__int_as_float(rs));
    }

    if (lane < 32) {
        const int s   = t & (S_LEN - 1);
        const int cb  = (t & 63) * DK + q * 4;
        const int rb  = ((t >> 11) << 11) + (s >> 6);
        #pragma unroll
        for (int nb = 0; nb < 4; ++nb) {
            const int h   = nb * 16 + l;
            const int row = rb + h * 32;
            f16x4 o;
            #pragma unroll
            for (int r = 0; r < 4; ++r) o[r] = (f16)(d2[nb][r] * rsinv[nb]);
            __builtin_nontemporal_store(o, (f16x4*)(A + (size_t)row * E_DIM + cb));
        }
    }
}

// ---------------------------------------------------------------------------
// Kernel 2: OUT = A @ W^T + bias. (unchanged — validated: BN=512 single-
// reader A, W L2-resident, nontemporal A/OUT streams, grid 512 = 2/CU.)
// ---------------------------------------------------------------------------
#define GBM 32
#define GBK 32

__global__ __launch_bounds__(256) void gemm_bias(
    const f16* __restrict__ A,        // 16384 x 512 f16 (ws)
    const f16* __restrict__ W,        // 512 x 512 f16 (ws)
    const float* __restrict__ BIAS,   // 512 fp32
    float* __restrict__ OUT)          // 16384 x 512 fp32
{
    __shared__ __align__(16) f16 ldsA[GBM * GBK];   // 2 KB
    __shared__ __align__(16) f16 ldsB[512 * GBK];   // 32 KB
    __shared__ __align__(16) float ldsT[4][16 * 132];          // 33.8 KB
    const int tid  = threadIdx.x;
    const int lane = tid & 63;
    const int wave = tid >> 6;
    const int quad = lane >> 4;
    const int l16  = lane & 15;
    const int m0 = blockIdx.x * GBM;
    const int wn = wave * 128;               // wave's global n-offset

    f32x4 acc[2][8] = {};

    for (int kb = 0; kb < 512; kb += GBK) {
        u32x4 wv8[8];
        int wr[8], wsx[8];
        #pragma unroll
        for (int i = 0; i < 8; ++i) {
            const int c  = tid + i * 256;
            const int r  = c >> 2;            // W row 0..511
            const int cc = c & 3;             // chunk in row
            wr[i]  = r;
            wsx[i] = ((cc ^ (r & 3) ^ ((r >> 2) & 3))) * 8;
            wv8[i] = *(const u32x4*)(W + (size_t)r * 512 + kb + cc * 8);
        }
        u32x4 aval; int arow = 0, asx = 0;
        if (tid < 128) {
            const int r  = tid >> 2;          // 0..31
            const int cc = tid & 3;
            arow = r;
            asx  = ((cc ^ (r & 3) ^ ((r >> 2) & 3))) * 8;
            aval = __builtin_nontemporal_load(
                       (const u32x4*)(A + (size_t)(m0 + r) * 512 + kb + cc * 8));
        }
        __syncthreads();   // previous iteration's readers done
        #pragma unroll
        for (int i = 0; i < 8; ++i)
            *(u32x4*)(ldsB + wr[i] * GBK + wsx[i]) = wv8[i];
        if (tid < 128)
            *(u32x4*)(ldsA + arow * GBK + asx) = aval;
        __syncthreads();   // staging visible

        f16x8 bfr[8];
        #pragma unroll
        for (int ni = 0; ni < 8; ++ni) {
            const int rw = wn + ni * 16 + l16;
            const int sw = ((quad ^ (rw & 3) ^ ((rw >> 2) & 3))) * 8;
            bfr[ni] = *(const f16x8*)(ldsB + rw * GBK + sw);
        }
        #pragma unroll
        for (int mi = 0; mi < 2; ++mi) {
            const int ra = mi * 16 + l16;
            const int sa = ((quad ^ (ra & 3) ^ ((ra >> 2) & 3))) * 8;
            const f16x8 afr = *(const f16x8*)(ldsA + ra * GBK + sa);
            #pragma unroll
            for (int ni = 0; ni < 8; ++ni)
                acc[mi][ni] = __builtin_amdgcn_mfma_f32_16x16x32_f16(
                    afr, bfr[ni], acc[mi][ni], 0, 0, 0);
        }
    }

    const int c4 = lane & 31;                 // fixed col-group per lane
    float4 bias4 = *(const float4*)(BIAS + wn + c4 * 4);
    #pragma unroll
    for (int mi = 0; mi < 2; ++mi) {
        __syncthreads();   // prior pass reads (or K-loop LDS use) done
        #pragma unroll
        for (int ni = 0; ni < 8; ++ni) {
            #pragma unroll
            for (int r = 0; r < 4; ++r)
                ldsT[wave][(quad * 4 + r) * 132 + ni * 16 + l16] = acc[mi][ni][r];
        }
        __syncthreads();   // transpose visible
        #pragma unroll
        for (int j = 0; j < 8; ++j) {
            const int row = j * 2 + (lane >> 5);       // 0..15
            f32x4 v = *(const f32x4*)&ldsT[wave][row * 132 + c4 * 4];
            v.x += bias4.x; v.y += bias4.y; v.z += bias4.z; v.w += bias4.w;
            float* o = OUT + (size_t)(m0 + mi * 16 + row) * 512 + wn + c4 * 4;
            __builtin_nontemporal_store(v, (f32x4*)o);
        }
    }
}

extern "C" void kernel_launch(void* const* d_in, const int* in_sizes, int n_in,
                              void* d_out, int out_size, void* d_ws, size_t ws_size,
                              hipStream_t stream) {
    const float* X  = (const float*)d_in[0];   // x fp32
    const float* TH = (const float*)d_in[1];   // theta fp32
    const float* W  = (const float*)d_in[2];   // W_combine fp32
    const float* BI = (const float*)d_in[3];   // b_combine fp32
    float* OUT = (float*)d_out;                // fp32

    f16* A  = (f16*)d_ws;                        // 16 MiB
    f16* Wb = (f16*)((char*)d_ws + (16u << 20)); // 512 KiB

    attn_stage<<<dim3(4096), dim3(256), 0, stream>>>(X, TH, W, Wb, A);
    gemm_bias<<<dim3(512), dim3(256), 0, stream>>>(A, Wb, BI, OUT);
}

// Round 14
// 116.518 us; speedup vs baseline: 1.0869x; 1.0869x over previous
//
#include <hip/hip_runtime.h>

typedef __attribute__((ext_vector_type(2))) float  f32x2;
typedef __attribute__((ext_vector_type(4))) float  f32x4;
typedef __attribute__((ext_vector_type(4))) unsigned int u32x4;
typedef _Float16 f16;
typedef __attribute__((ext_vector_type(2))) _Float16 f16x2;
typedef __attribute__((ext_vector_type(4))) _Float16 f16x4;
typedef __attribute__((ext_vector_type(8))) _Float16 f16x8;

#define S_LEN 2048
#define E_DIM 512
#define NH 64
#define DK 8

// ---------------------------------------------------------------------------
// Kernel 1: MFMA attention (R11 design; R12 measured ~25us). One wave=token.
// S2 = Ps·Psᵀ (16 MFMA), E = exp2(S2) row-major via symmetry, D2 =
// [Pᵀ; ones]·Eᵀ (8 MFMA, row 8 = denominators), bpermute+rcp, f16x4 stores.
// R14: A-stores are NORMAL (R13's nontemporal 8B scattered stores caused ~4x
// write amplification + L2-miss on gemm's A reads: +7us. nt is only for
// full-line single-use streams). convert_w stays fused (blocks 0..255).
// A[row,col]: row = b*2048 + h*32 + s/64 ; col = (s%64)*8 + d  (f16)
// ---------------------------------------------------------------------------
__global__ __launch_bounds__(256) void attn_stage(
    const float* __restrict__ X,    // (8,2048,512) fp32
    const float* __restrict__ TH,   // (8,) fp32
    const float* __restrict__ W,    // (512,512) fp32
    f16* __restrict__ Wb,           // ws: 512x512 f16
    f16* __restrict__ A)            // ws: 16384 x 512 fp16
{
    __shared__ __align__(16) f16 Ps[4][NH][DK];   // 4 KB
    __shared__ __align__(16) f16 Pt[4][16][72];   // 9 KB
    __shared__ __align__(16) f16 Ev[4][NH * NH];  // 32 KB
    const int tid  = threadIdx.x;
    const int wv   = tid >> 6;
    const int lane = tid & 63;
    const int q    = lane >> 4;
    const int l    = lane & 15;
    const int t    = blockIdx.x * 4 + wv;    // token id

    // Side job: W fp32 -> f16 (65536 float4s == 256 blocks x 256 threads)
    if (blockIdx.x < 256) {
        const int i = blockIdx.x * 256 + tid;
        const float4 v = *(const float4*)(W + (size_t)i * 4);
        f16x4 o = {(f16)v.x, (f16)v.y, (f16)v.z, (f16)v.w};
        *(f16x4*)(Wb + (size_t)i * 4) = o;
    }

    const float4 t0 = *(const float4*)(TH);
    const float4 t1 = *(const float4*)(TH + 4);
    const float4 x0 = *(const float4*)(X + (size_t)t * E_DIM + lane * DK);
    const float4 x1 = *(const float4*)(X + (size_t)t * E_DIM + lane * DK + 4);

    float p[DK];
    p[0] = __cosf(x0.x + t0.x); p[1] = __cosf(x0.y + t0.y);
    p[2] = __cosf(x0.z + t0.z); p[3] = __cosf(x0.w + t0.w);
    p[4] = __cosf(x1.x + t1.x); p[5] = __cosf(x1.y + t1.y);
    p[6] = __cosf(x1.z + t1.z); p[7] = __cosf(x1.w + t1.w);

    // Ps[h][d] = p*cs  (cs^2 = (1/sqrt(8))*log2(e))
    const float cs = 0.714227053f;
    f16x8 psv;
    #pragma unroll
    for (int d = 0; d < DK; ++d) psv[d] = (f16)(p[d] * cs);
    *(f16x8*)&Ps[wv][lane][0] = psv;
    #pragma unroll
    for (int d = 0; d < DK; ++d) Pt[wv][d][lane] = (f16)p[d];
    __syncthreads();

    const f16x8 z8  = {(f16)0,(f16)0,(f16)0,(f16)0,(f16)0,(f16)0,(f16)0,(f16)0};
    const f16x8 one8= {(f16)1,(f16)1,(f16)1,(f16)1,(f16)1,(f16)1,(f16)1,(f16)1};

    f16x8 f[4];
    #pragma unroll
    for (int i = 0; i < 4; ++i) {
        const f16x8 v = *(const f16x8*)&Ps[wv][i*16 + l][0];
        f[i] = (q == 0) ? v : z8;
    }
    f32x4 St[4][4];
    #pragma unroll
    for (int i = 0; i < 4; ++i)
        #pragma unroll
        for (int jb = 0; jb < 4; ++jb) {
            f32x4 zc = {0.f, 0.f, 0.f, 0.f};
            St[i][jb] = __builtin_amdgcn_mfma_f32_16x16x32_f16(f[i], f[jb], zc, 0, 0, 0);
        }

    // E = exp2(S2), row-major via symmetry; chunk-8 XOR swizzle on cols.
    #pragma unroll
    for (int i = 0; i < 4; ++i)
        #pragma unroll
        for (int jb = 0; jb < 4; ++jb) {
            const float e0 = __builtin_amdgcn_exp2f(St[i][jb][0]);
            const float e1 = __builtin_amdgcn_exp2f(St[i][jb][1]);
            const float e2 = __builtin_amdgcn_exp2f(St[i][jb][2]);
            const float e3 = __builtin_amdgcn_exp2f(St[i][jb][3]);
            f16x4 w4;
            w4[0] = (f16)e0; w4[1] = (f16)e1; w4[2] = (f16)e2; w4[3] = (f16)e3;
            const int row = jb * 16 + l;
            const int c8  = (i * 2 + (q >> 1)) ^ (l & 7);
            const int col = c8 * 8 + (q & 1) * 4;
            *(f16x4*)&Ev[wv][row * 64 + col] = w4;
        }
    __syncthreads();

    // D2 = [Pᵀ; ones; 0]·Eᵀ over K=64.
    f32x4 d2[4] = {};
    #pragma unroll
    for (int kh = 0; kh < 2; ++kh) {
        const f16x8 av  = *(const f16x8*)&Pt[wv][l][kh * 32 + q * 8];
        const f16x8 a2f = (l < 8) ? av : ((l == 8) ? one8 : z8);
        #pragma unroll
        for (int nb = 0; nb < 4; ++nb) {
            const int c8 = (kh * 4 + q) ^ (l & 7);
            const f16x8 bv = *(const f16x8*)&Ev[wv][(nb * 16 + l) * 64 + c8 * 8];
            d2[nb] = __builtin_amdgcn_mfma_f32_16x16x32_f16(a2f, bv, d2[nb], 0, 0, 0);
        }
    }

    float rsinv[4];
    #pragma unroll
    for (int nb = 0; nb < 4; ++nb) {
        const int rs = __builtin_amdgcn_ds_bpermute((32 + l) * 4,
                           __float_as_int(d2[nb][0]));
        rsinv[nb] = __builtin_amdgcn_rcpf(__int_as_float(rs));
    }

    if (lane < 32) {
        const int s   = t & (S_LEN - 1);
        const int cb  = (t & 63) * DK + q * 4;
        const int rb  = ((t >> 11) << 11) + (s >> 6);
        #pragma unroll
        for (int nb = 0; nb < 4; ++nb) {
            const int h   = nb * 16 + l;
            const int row = rb + h * 32;
            f16x4 o;
            #pragma unroll
            for (int r = 0; r < 4; ++r) o[r] = (f16)(d2[nb][r] * rsinv[nb]);
            *(f16x4*)(A + (size_t)row * E_DIM + cb) = o;   // normal store (L2-merged)
        }
    }
}

// ---------------------------------------------------------------------------
// Kernel 2: OUT = A @ W^T + bias. (unchanged — validated: BN=512 single-
// reader A, W L2-resident, nontemporal A/OUT streams, grid 512 = 2/CU.)
// ---------------------------------------------------------------------------
#define GBM 32
#define GBK 32

__global__ __launch_bounds__(256) void gemm_bias(
    const f16* __restrict__ A,        // 16384 x 512 f16 (ws)
    const f16* __restrict__ W,        // 512 x 512 f16 (ws)
    const float* __restrict__ BIAS,   // 512 fp32
    float* __restrict__ OUT)          // 16384 x 512 fp32
{
    __shared__ __align__(16) f16 ldsA[GBM * GBK];   // 2 KB
    __shared__ __align__(16) f16 ldsB[512 * GBK];   // 32 KB
    __shared__ __align__(16) float ldsT[4][16 * 132];          // 33.8 KB
    const int tid  = threadIdx.x;
    const int lane = tid & 63;
    const int wave = tid >> 6;
    const int quad = lane >> 4;
    const int l16  = lane & 15;
    const int m0 = blockIdx.x * GBM;
    const int wn = wave * 128;               // wave's global n-offset

    f32x4 acc[2][8] = {};

    for (int kb = 0; kb < 512; kb += GBK) {
        u32x4 wv8[8];
        int wr[8], wsx[8];
        #pragma unroll
        for (int i = 0; i < 8; ++i) {
            const int c  = tid + i * 256;
            const int r  = c >> 2;            // W row 0..511
            const int cc = c & 3;             // chunk in row
            wr[i]  = r;
            wsx[i] = ((cc ^ (r & 3) ^ ((r >> 2) & 3))) * 8;
            wv8[i] = *(const u32x4*)(W + (size_t)r * 512 + kb + cc * 8);
        }
        u32x4 aval; int arow = 0, asx = 0;
        if (tid < 128) {
            const int r  = tid >> 2;          // 0..31
            const int cc = tid & 3;
            arow = r;
            asx  = ((cc ^ (r & 3) ^ ((r >> 2) & 3))) * 8;
            aval = __builtin_nontemporal_load(
                       (const u32x4*)(A + (size_t)(m0 + r) * 512 + kb + cc * 8));
        }
        __syncthreads();   // previous iteration's readers done
        #pragma unroll
        for (int i = 0; i < 8; ++i)
            *(u32x4*)(ldsB + wr[i] * GBK + wsx[i]) = wv8[i];
        if (tid < 128)
            *(u32x4*)(ldsA + arow * GBK + asx) = aval;
        __syncthreads();   // staging visible

        f16x8 bfr[8];
        #pragma unroll
        for (int ni = 0; ni < 8; ++ni) {
            const int rw = wn + ni * 16 + l16;
            const int sw = ((quad ^ (rw & 3) ^ ((rw >> 2) & 3))) * 8;
            bfr[ni] = *(const f16x8*)(ldsB + rw * GBK + sw);
        }
        #pragma unroll
        for (int mi = 0; mi < 2; ++mi) {
            const int ra = mi * 16 + l16;
            const int sa = ((quad ^ (ra & 3) ^ ((ra >> 2) & 3))) * 8;
            const f16x8 afr = *(const f16x8*)(ldsA + ra * GBK + sa);
            #pragma unroll
            for (int ni = 0; ni < 8; ++ni)
                acc[mi][ni] = __builtin_amdgcn_mfma_f32_16x16x32_f16(
                    afr, bfr[ni], acc[mi][ni], 0, 0, 0);
        }
    }

    const int c4 = lane & 31;                 // fixed col-group per lane
    float4 bias4 = *(const float4*)(BIAS + wn + c4 * 4);
    #pragma unroll
    for (int mi = 0; mi < 2; ++mi) {
        __syncthreads();   // prior pass reads (or K-loop LDS use) done
        #pragma unroll
        for (int ni = 0; ni < 8; ++ni) {
            #pragma unroll
            for (int r = 0; r < 4; ++r)
                ldsT[wave][(quad * 4 + r) * 132 + ni * 16 + l16] = acc[mi][ni][r];
        }
        __syncthreads();   // transpose visible
        #pragma unroll
        for (int j = 0; j < 8; ++j) {
            const int row = j * 2 + (lane >> 5);       // 0..15
            f32x4 v = *(const f32x4*)&ldsT[wave][row * 132 + c4 * 4];
            v.x += bias4.x; v.y += bias4.y; v.z += bias4.z; v.w += bias4.w;
            float* o = OUT + (size_t)(m0 + mi * 16 + row) * 512 + wn + c4 * 4;
            __builtin_nontemporal_store(v, (f32x4*)o);
        }
    }
}

extern "C" void kernel_launch(void* const* d_in, const int* in_sizes, int n_in,
                              void* d_out, int out_size, void* d_ws, size_t ws_size,
                              hipStream_t stream) {
    const float* X  = (const float*)d_in[0];   // x fp32
    const float* TH = (const float*)d_in[1];   // theta fp32
    const float* W  = (const float*)d_in[2];   // W_combine fp32
    const float* BI = (const float*)d_in[3];   // b_combine fp32
    float* OUT = (float*)d_out;                // fp32

    f16* A  = (f16*)d_ws;                        // 16 MiB
    f16* Wb = (f16*)((char*)d_ws + (16u << 20)); // 512 KiB

    attn_stage<<<dim3(4096), dim3(256), 0, stream>>>(X, TH, W, Wb, A);
    gemm_bias<<<dim3(512), dim3(256), 0, stream>>>(A, Wb, BI, OUT);
}